// Round 6
// baseline (416.204 us; speedup 1.0000x reference)
//
#include <hip/hip_runtime.h>
#include <hip/hip_bf16.h>
#include <hip/hip_fp16.h>

#define NN 50000
#define NE 800000
#define NG 64
#define C1 128    // H1*D1
#define D2 32
#define CAP 32    // capped slots per node; overflow handled exactly via ovf buffer
#define EPT 4     // edges per thread in k_prep (pipelined chains)
#define PBLK 782  // ceil(NE / (256*EPT))
#define L1BLK 1280 // k_layer1: 5 blocks/CU (27.1KB LDS cap) -> full residency + staging cut
#define FBLK 2048  // k_final: 8 blocks/CU (18KB LDS cap) x ~3 node-groups each
#define BN_EPS 1e-5f

// ---- constant-block layout (float offsets inside cst) ----
#define CST_A   0
#define CST_B   2
#define CST_P   4
#define CST_Q   132
#define CST_R   260
#define CST_SC2 388
#define CST_RC2 420
#define CST_SD  452
#define CST_RD  580
#define CST_N   1024

// ---- workspace layout (4-byte-unit offsets inside d_ws), ~23 MiB ----
#define UO_DEGP  0                        // int[16*NN] padded: one counter per 64B line (zeroed)
#define UO_OVFC  800000                   // int[1]   (zeroed, padded)
#define ZERO_UNITS 800016
#define UO_FLAG  800016                   // int[1]
#define UO_CST   800032                   // float[CST_N]
#define UO_ESRC2 801056                   // ushort[CAP*NN] padded edge table (64B-aligned rows)
#define UO_OVF   1601056                  // int2[NE] overflow (dst,src)
#define UO_FCAN  3201056                  // float[NN]
#define UO_F2    3251056                  // ushort[D2*NN] bf16 (16B aligned)
#define UO_RS2   4051056                  // float[D2*NN]; overwritten with h2 by k_final
#define UO_EL2   5651056                  // float[NN]
#define UO_ER2   5701056                  // float[NN]

typedef _Float16 h2vec __attribute__((ext_vector_type(2)));

__device__ __forceinline__ float lrelu(float x) { return fmaxf(x, 0.2f * x); }
__device__ __forceinline__ float bu2f(unsigned int u) {
    union { unsigned int i; float f; } v; v.i = (u & 0xFFFFu) << 16; return v.f;
}
__device__ __forceinline__ unsigned short f2bu(float f) {
    union { float f; unsigned int i; } v; v.f = f;
    unsigned int r = v.i + 0x7FFFu + ((v.i >> 16) & 1u);
    return (unsigned short)(r >> 16);
}
__device__ __forceinline__ unsigned int packh2(float a, float b) {
    h2vec h; h.x = (_Float16)a; h.y = (_Float16)b;
    union { h2vec h; unsigned int u; } v; v.h = h; return v.u;
}
__device__ __forceinline__ h2vec as_h2(unsigned int u) {
    union { unsigned int u; h2vec h; } v; v.u = u; return v.h;
}
__device__ __forceinline__ float ldw(const void* p, int i, int bf) {
    return bf ? bu2f(((const unsigned short*)p)[i]) : ((const float*)p)[i];
}
__device__ __forceinline__ int sniff64(const unsigned int* fw, int l) {
    int cnt = 0;
    for (int j = l; j < 256; j += 64) {
        unsigned int b = (fw[j] >> 8) & 0x7Fu;
        cnt += (b >= 0x3Au && b <= 0x41u) ? 1 : 0;
    }
#pragma unroll
    for (int m = 32; m >= 1; m >>= 1) cnt += __shfl_xor(cnt, m);
    return (cnt > 128) ? 1 : 0;
}

// ---------------- edge-table build: single-pass, explicitly pipelined atomic chains ----------------
// (R5-verified: k_prep dropped out of top-5 with this structure; do not touch.)
__global__ __launch_bounds__(256) void k_prep(
                       const void* __restrict__ feat, const int* __restrict__ dst,
                       const int* __restrict__ src,
                       float* __restrict__ fcan, int* __restrict__ degp,
                       unsigned short* __restrict__ esrc2,
                       int2* __restrict__ ovf, int* __restrict__ ovfc,
                       const void* W1, const void* al1, const void* ar1,
                       const void* res1, const void* b1,
                       const void* g1g, const void* g1b, const void* g1m, const void* g1v,
                       const void* b2v, const void* g2g, const void* g2b,
                       const void* g2m, const void* g2v,
                       const void* bd1, const void* gdg, const void* gdb,
                       const void* gdm, const void* gdv,
                       int* __restrict__ flag, float* __restrict__ cst) {
    __shared__ int sBf;
    int t = threadIdx.x;
    if (t < 64) {
        int b = sniff64((const unsigned int*)feat, t);
        if (t == 0) sBf = b;
    }
    __syncthreads();
    int bf = sBf;

    if (blockIdx.x == 0) {     // fold tiny weights into fp32 constants (tree-parallel)
        if (t == 0) *flag = bf;
        if (t < 128) {
            float w1v = ldw(W1, t, bf);
            float pa = w1v * ldw(al1, t, bf);
            float pb = w1v * ldw(ar1, t, bf);
#pragma unroll
            for (int m = 32; m >= 1; m >>= 1) { pa += __shfl_xor(pa, m); pb += __shfl_xor(pb, m); }
            if ((t & 63) == 0) { cst[CST_A + (t >> 6)] = pa; cst[CST_B + (t >> 6)] = pb; }
            float sc = rsqrtf(ldw(g1v, t, bf) + BN_EPS) * ldw(g1g, t, bf);
            cst[CST_P + t] = w1v * sc;
            cst[CST_Q + t] = ldw(res1, t, bf) * sc;
            cst[CST_R + t] = (ldw(b1, t, bf) - ldw(g1m, t, bf)) * sc + ldw(g1b, t, bf);
            if (t < D2) {
                float s2 = rsqrtf(ldw(g2v, t, bf) + BN_EPS) * ldw(g2g, t, bf);
                cst[CST_SC2 + t] = s2;
                cst[CST_RC2 + t] = (ldw(b2v, t, bf) - ldw(g2m, t, bf)) * s2 + ldw(g2b, t, bf);
            }
            float sd = rsqrtf(ldw(gdv, t, bf) + BN_EPS) * ldw(gdg, t, bf);
            cst[CST_SD + t] = sd;
            cst[CST_RD + t] = (ldw(bd1, t, bf) - ldw(gdm, t, bf)) * sd + ldw(gdb, t, bf);
        }
    }

    // fcan conversion, grid-stride (<=1 iter/thread at this grid)
    for (int k = blockIdx.x * 256 + t; k < NN; k += PBLK * 256)
        fcan[k] = ldw(feat, k, bf);

    // phase a: load EPT edges (independent coalesced loads)
    int base = blockIdx.x * (256 * EPT) + t;
    int dv[EPT], sv[EPT];
    bool vv[EPT];
#pragma unroll
    for (int j = 0; j < EPT; ++j) {
        int k = base + j * 256;
        vv[j] = (k < NE);
        dv[j] = vv[j] ? dst[k] : 0;
        sv[j] = vv[j] ? src[k] : 0;
    }
    // phase b: issue all slot atomics back-to-back (independent round trips)
    int slot[EPT];
#pragma unroll
    for (int j = 0; j < EPT; ++j)
        if (vv[j]) slot[j] = atomicAdd(&degp[dv[j] << 4], 1);
    __builtin_amdgcn_sched_barrier(0);   // keep stores from sinking between atomic issues
    // phase c: consume slots
#pragma unroll
    for (int j = 0; j < EPT; ++j) {
        if (vv[j]) {
            if (slot[j] < CAP) {
                esrc2[dv[j] * CAP + slot[j]] = (unsigned short)sv[j];
            } else {
                int p = atomicAdd(ovfc, 1);    // rare
                ovf[p] = make_int2(dv[j], sv[j]);
            }
        }
    }
}

// ---------------- layer-1: 1280 blocks = 5/CU (LDS-cap residency) + staging amortized ----------
__global__ __launch_bounds__(256) void k_layer1(
        const float* __restrict__ fcan, const void* W2, const void* res2,
        const void* al2, const void* ar2,
        const int* __restrict__ flag, const float* __restrict__ cst,
        const int* __restrict__ degp, const unsigned short* __restrict__ esrc2,
        const int2* __restrict__ ovf, const int* __restrict__ ovfc,
        unsigned short* __restrict__ F2, float* __restrict__ RS2,
        float* __restrict__ EL2, float* __restrict__ ER2) {
    __shared__ unsigned int sW2pk[32 * 66];  // [l][cw], (c,c+64) f16 pairs
    __shared__ unsigned int sR2pk[32 * 66];
    __shared__ unsigned int sH1pk[32 * 66];
    __shared__ float sP[C1], sQ[C1], sR[C1];
    __shared__ float sAl[D2], sAr[D2];
    int t = threadIdx.x;
    int bf = *flag;
    for (int u = t; u < 2048; u += 256) {
        int cw = u >> 5, l2 = u & 31;
        sW2pk[l2 * 66 + cw] = packh2(ldw(W2, cw * D2 + l2, bf),
                                     ldw(W2, (cw + 64) * D2 + l2, bf));
        sR2pk[l2 * 66 + cw] = packh2(ldw(res2, cw * D2 + l2, bf),
                                     ldw(res2, (cw + 64) * D2 + l2, bf));
    }
    if (t < C1) { sP[t] = cst[CST_P + t]; sQ[t] = cst[CST_Q + t]; sR[t] = cst[CST_R + t]; }
    if (t < D2) { sAl[t] = ldw(al2, t, bf); sAr[t] = ldw(ar2, t, bf); }
    float A0 = cst[CST_A + 0], A1 = cst[CST_A + 1];
    float B0 = cst[CST_B + 0], B1 = cst[CST_B + 1];
    __syncthreads();

    int l = t & 31;
    int g = t >> 5;
    int w = t >> 6, half = (t >> 5) & 1, nb0 = w * 8 + half * 4;

    for (int base = blockIdx.x * 32; base < NN; base += L1BLK * 32) {
        int dcap[4], draw[4];
        float fiK[4];
#pragma unroll
        for (int k = 0; k < 4; ++k) {
            int i = base + g * 4 + k;
            if (i < NN) {
                draw[k] = degp[i << 4];
                dcap[k] = draw[k] < CAP ? draw[k] : CAP;
                fiK[k] = fcan[i];
            } else { draw[k] = 0; dcap[k] = 0; fiK[k] = 0.0f; }
        }
        float S0[4], S1[4], N0[4], N1[4];
#pragma unroll
        for (int k = 0; k < 4; ++k) { S0[k] = S1[k] = N0[k] = N1[k] = 0.0f; }
        int sA[4];
#pragma unroll
        for (int k = 0; k < 4; ++k)
            sA[k] = (l < dcap[k]) ? (int)esrc2[(base + g * 4 + k) * CAP + l] : 0;
        float fA[4];
#pragma unroll
        for (int k = 0; k < 4; ++k) fA[k] = fcan[sA[k]];
#pragma unroll
        for (int k = 0; k < 4; ++k) {
            if (l < dcap[k]) {
                float w0 = __expf(lrelu(A0 * fA[k] + B0 * fiK[k]));
                float w1 = __expf(lrelu(A1 * fA[k] + B1 * fiK[k]));
                S0[k] += w0; N0[k] += w0 * fA[k];
                S1[k] += w1; N1[k] += w1 * fA[k];
            }
        }
        // rare overflow edges (deg > CAP)
#pragma unroll
        for (int k = 0; k < 4; ++k) {
            if (draw[k] > CAP) {
                int i = base + g * 4 + k;
                int novf = *ovfc;
                for (int p = l; p < novf; p += 32) {
                    int2 o = ovf[p];
                    if (o.x == i) {
                        float fs = fcan[o.y];
                        float w0 = __expf(lrelu(A0 * fs + B0 * fiK[k]));
                        float w1 = __expf(lrelu(A1 * fs + B1 * fiK[k]));
                        S0[k] += w0; N0[k] += w0 * fs;
                        S1[k] += w1; N1[k] += w1 * fs;
                    }
                }
            }
        }
#pragma unroll
        for (int m = 16; m >= 1; m >>= 1) {
#pragma unroll
            for (int k = 0; k < 4; ++k) {
                S0[k] += __shfl_xor(S0[k], m); N0[k] += __shfl_xor(N0[k], m);
                S1[k] += __shfl_xor(S1[k], m); N1[k] += __shfl_xor(N1[k], m);
            }
        }
#pragma unroll
        for (int k = 0; k < 4; ++k) {
            int slot = g * 4 + k;
            float T0 = S0[k] > 0.0f ? N0[k] / S0[k] : 0.0f;
            float T1 = S1[k] > 0.0f ? N1[k] / S1[k] : 0.0f;
            float h0  = fmaxf(sP[l]      * T0 + sQ[l]      * fiK[k] + sR[l],      0.0f);
            float h1v = fmaxf(sP[l + 32] * T0 + sQ[l + 32] * fiK[k] + sR[l + 32], 0.0f);
            float h2v = fmaxf(sP[l + 64] * T1 + sQ[l + 64] * fiK[k] + sR[l + 64], 0.0f);
            float h3v = fmaxf(sP[l + 96] * T1 + sQ[l + 96] * fiK[k] + sR[l + 96], 0.0f);
            sH1pk[slot * 66 + l]      = packh2(h0,  h2v);   // (c, c+64) f16 pair
            sH1pk[slot * 66 + l + 32] = packh2(h1v, h3v);
        }
        __syncthreads();

        // --- phase 2: v_dot2_f32_f16 — one inst per (c,c+64) pair, fp32 accumulate
        float aF[4] = {0.f, 0.f, 0.f, 0.f}, aR[4] = {0.f, 0.f, 0.f, 0.f};
        for (int cw = 0; cw < 64; cw += 2) {
            uint2 wq = *(const uint2*)&sW2pk[l * 66 + cw];
            uint2 rq = *(const uint2*)&sR2pk[l * 66 + cw];
#pragma unroll
            for (int n = 0; n < 4; ++n) {
                uint2 hq = *(const uint2*)&sH1pk[(nb0 + n) * 66 + cw];   // broadcast
                aF[n] = __builtin_amdgcn_fdot2(as_h2(hq.x), as_h2(wq.x),
                        __builtin_amdgcn_fdot2(as_h2(hq.y), as_h2(wq.y), aF[n], false), false);
                aR[n] = __builtin_amdgcn_fdot2(as_h2(hq.x), as_h2(rq.x),
                        __builtin_amdgcn_fdot2(as_h2(hq.y), as_h2(rq.y), aR[n], false), false);
            }
        }
#pragma unroll
        for (int n = 0; n < 4; ++n) {
            int i = base + nb0 + n;
            if (i < NN) {
                float elp = aF[n] * sAl[l], erp = aF[n] * sAr[l];
#pragma unroll
                for (int m = 16; m >= 1; m >>= 1) {
                    elp += __shfl_xor(elp, m);
                    erp += __shfl_xor(erp, m);
                }
                if (l == 0) { EL2[i] = elp; ER2[i] = erp; }
                F2[(size_t)i * D2 + l]  = f2bu(aF[n]);
                RS2[(size_t)i * D2 + l] = aR[n];
            }
        }
        __syncthreads();   // H1pk reused next tile
    }
}

// ---------------- layer-2 gather + decoder: Wd1 staged ONCE per block, ~3 node-groups each ----
// R5 showed the 6250-block version issued as many staging ops (25.6M) as gather loads;
// 2048 blocks keeps the same 8-blocks/CU residency while cutting staging 3x.
__global__ __launch_bounds__(256, 8) void k_final(
        const void* Wd1, const void* Wd2, const void* bd2,
        const int* __restrict__ flag, const float* __restrict__ cst,
        const int* __restrict__ degp, const unsigned short* __restrict__ esrc2,
        const int2* __restrict__ ovf, const int* __restrict__ ovfc,
        const unsigned short* __restrict__ F2, float* __restrict__ RS2,
        const float* __restrict__ EL2, const float* __restrict__ ER2,
        float* __restrict__ out) {
    __shared__ float sWd1x[4096];        // [d][lane][4] = {W[d][l], W[d][l+32], W[d][l+64], W[d][l+96]}
    __shared__ unsigned int sWS[8 * 64]; // per-group (w,s) pairs
    int t = threadIdx.x;
    int bf = *flag;
    for (int u = t; u < 4096; u += 256) {
        int d = u >> 7, lq = (u >> 2) & 31, j = u & 3;
        sWd1x[u] = ldw(Wd1, d * C1 + j * 32 + lq, bf);
    }

    int l = t & 31;
    int nb = t >> 5;

    // per-lane loop-invariant constants (registers, not LDS)
    float sc2 = cst[CST_SC2 + l], rc2 = cst[CST_RC2 + l];
    float sd0 = cst[CST_SD + l],      rd0 = cst[CST_RD + l];
    float sd1 = cst[CST_SD + l + 32], rd1 = cst[CST_RD + l + 32];
    float sd2 = cst[CST_SD + l + 64], rd2 = cst[CST_RD + l + 64];
    float sd3 = cst[CST_SD + l + 96], rd3 = cst[CST_RD + l + 96];
    float wd2_0 = ldw(Wd2, l, bf),      wd2_1 = ldw(Wd2, l + 32, bf);
    float wd2_2 = ldw(Wd2, l + 64, bf), wd2_3 = ldw(Wd2, l + 96, bf);
    float bd2v  = ldw(bd2, 0, bf);
    __syncthreads();

    const float4* Wx = (const float4*)sWd1x;
    for (int i0 = blockIdx.x * 8; i0 < NN; i0 += FBLK * 8) {
        int i = i0 + nb;                                 // NN % 8 == 0 -> always < NN
        float eri = ER2[i];
        int dr = degp[i << 4];
        int dcap = dr < CAP ? dr : CAP;
        const unsigned short* row = &esrc2[i * CAP];

        // --- per-lane w: lane l owns edge l (exp computed ONCE per edge)
        int sMy = 0; float wMy = 0.0f;
        if (l < dcap) {
            sMy = (int)row[l];
            wMy = __expf(lrelu(EL2[sMy] + eri));
        }
        float S = wMy;
#pragma unroll
        for (int m = 16; m >= 1; m >>= 1) S += __shfl_xor(S, m);
        sWS[nb * 64 + 2 * l]     = __float_as_uint(wMy);   // wave-synchronous: same wave
        sWS[nb * 64 + 2 * l + 1] = (unsigned int)sMy;      // writes then reads, in order

        float aF0 = 0.f, aF1 = 0.f, aF2 = 0.f, aF3 = 0.f;
        int e = 0;
        for (; e + 3 < dcap; e += 4) {
            uint2 p0 = *(const uint2*)&sWS[nb * 64 + 2 * e];
            uint2 p1 = *(const uint2*)&sWS[nb * 64 + 2 * (e + 1)];
            uint2 p2 = *(const uint2*)&sWS[nb * 64 + 2 * (e + 2)];
            uint2 p3 = *(const uint2*)&sWS[nb * 64 + 2 * (e + 3)];
            float v0 = bu2f(F2[(p0.y << 5) + l]);          // 32-bit index: node*32+l
            float v1 = bu2f(F2[(p1.y << 5) + l]);
            float v2 = bu2f(F2[(p2.y << 5) + l]);
            float v3 = bu2f(F2[(p3.y << 5) + l]);
            aF0 = fmaf(__uint_as_float(p0.x), v0, aF0);
            aF1 = fmaf(__uint_as_float(p1.x), v1, aF1);
            aF2 = fmaf(__uint_as_float(p2.x), v2, aF2);
            aF3 = fmaf(__uint_as_float(p3.x), v3, aF3);
        }
        for (; e < dcap; ++e) {
            uint2 p = *(const uint2*)&sWS[nb * 64 + 2 * e];
            aF0 = fmaf(__uint_as_float(p.x), bu2f(F2[(p.y << 5) + l]), aF0);
        }
        if (dr > CAP) {
            int novf = *ovfc;
            for (int p = 0; p < novf; ++p) {
                int2 o = ovf[p];
                if (o.x == i) {
                    float wA = __expf(lrelu(EL2[o.y] + eri));
                    S += wA;
                    aF0 = fmaf(wA, bu2f(F2[((unsigned)o.y << 5) + l]), aF0);
                }
            }
        }
        float aF = (aF0 + aF1) + (aF2 + aF3);
        float inv = S > 0.0f ? 1.0f / S : 0.0f;

        float h2 = fmaxf((aF * inv + RS2[(size_t)i * D2 + l]) * sc2 + rc2, 0.0f);
        RS2[(size_t)i * D2 + l] = h2;

        // decoder: h2 broadcast via shuffle, one conflict-free ds_read_b128 per d
        float ac0 = 0.0f, ac1 = 0.0f, ac2 = 0.0f, ac3 = 0.0f;
#pragma unroll
        for (int d = 0; d < D2; ++d) {
            float h = __shfl(h2, d, 32);
            float4 wv = Wx[d * 32 + l];
            ac0 = fmaf(h, wv.x, ac0);
            ac1 = fmaf(h, wv.y, ac1);
            ac2 = fmaf(h, wv.z, ac2);
            ac3 = fmaf(h, wv.w, ac3);
        }
        float rec = fmaxf(ac0 * sd0 + rd0, 0.0f) * wd2_0
                  + fmaxf(ac1 * sd1 + rd1, 0.0f) * wd2_1
                  + fmaxf(ac2 * sd2 + rd2, 0.0f) * wd2_2
                  + fmaxf(ac3 * sd3 + rd3, 0.0f) * wd2_3;
#pragma unroll
        for (int m = 16; m >= 1; m >>= 1) rec += __shfl_xor(rec, m);
        if (l == 0) out[NG * D2 + i] = rec + bd2v;
    }
}

// ---------------- graph mean pool: one block per graph, direct write ----------
__global__ __launch_bounds__(256) void k_pool2(const int* __restrict__ gid,
                                               const float* __restrict__ H2,
                                               float* __restrict__ out) {
    __shared__ int sLo, sHi;
    __shared__ float sAcc[32 * 32];
    int g = blockIdx.x;
    int t = threadIdx.x;
    if (t == 0) {
        int lo = 0, hi = NN;
        while (lo < hi) { int m = (lo + hi) >> 1; if (gid[m] < g) lo = m + 1; else hi = m; }
        sLo = lo;
        lo = 0; hi = NN;
        while (lo < hi) { int m = (lo + hi) >> 1; if (gid[m] < g + 1) lo = m + 1; else hi = m; }
        sHi = lo;
    }
    __syncthreads();
    int lo = sLo, hi = sHi;
    int q = t & 7;
    int row = t >> 3;
    float4 acc = make_float4(0.f, 0.f, 0.f, 0.f);
    for (int i = lo + row; i < hi; i += 32) {
        float4 v = ((const float4*)&H2[(size_t)i * D2])[q];
        acc.x += v.x; acc.y += v.y; acc.z += v.z; acc.w += v.w;
    }
    *(float4*)&sAcc[row * 32 + 4 * q] = acc;
    __syncthreads();
    if (t < 32) {
        float a = 0.0f;
        for (int r = 0; r < 32; ++r) a += sAcc[r * 32 + t];
        float c = (float)(hi - lo);
        out[g * D2 + t] = a / fmaxf(c, 1.0f);
    }
}

extern "C" void kernel_launch(void* const* d_in, const int* in_sizes, int n_in,
                              void* d_out, int out_size, void* d_ws, size_t ws_size,
                              hipStream_t stream) {
    const void* feat = d_in[0];
    const void* W1 = d_in[1];  const void* al1 = d_in[2];  const void* ar1 = d_in[3];
    const void* res1 = d_in[4]; const void* b1 = d_in[5];
    const void* g1g = d_in[6]; const void* g1b = d_in[7];
    const void* g1m = d_in[8]; const void* g1v = d_in[9];
    const void* W2 = d_in[10]; const void* al2 = d_in[11]; const void* ar2 = d_in[12];
    const void* res2 = d_in[13]; const void* b2v = d_in[14];
    const void* g2g = d_in[15]; const void* g2b = d_in[16];
    const void* g2m = d_in[17]; const void* g2v = d_in[18];
    const void* Wd1 = d_in[19]; const void* bd1 = d_in[20];
    const void* gdg = d_in[21]; const void* gdb = d_in[22];
    const void* gdm = d_in[23]; const void* gdv = d_in[24];
    const void* Wd2 = d_in[25]; const void* bd2 = d_in[26];
    const int* src = (const int*)d_in[27];
    const int* dst = (const int*)d_in[28];
    const int* gid = (const int*)d_in[29];

    unsigned int* wsu = (unsigned int*)d_ws;
    int* degp   = (int*)(wsu + UO_DEGP);
    int* ovfc   = (int*)(wsu + UO_OVFC);
    int* flag   = (int*)(wsu + UO_FLAG);
    float* cst  = (float*)(wsu + UO_CST);
    unsigned short* esrc2 = (unsigned short*)(wsu + UO_ESRC2);
    int2* ovf   = (int2*)(wsu + UO_OVF);
    float* fcan = (float*)(wsu + UO_FCAN);
    unsigned short* F2 = (unsigned short*)(wsu + UO_F2);
    float* RS2  = (float*)(wsu + UO_RS2);
    float* EL2  = (float*)(wsu + UO_EL2);
    float* ER2  = (float*)(wsu + UO_ER2);

    hipMemsetAsync(d_ws, 0, (size_t)ZERO_UNITS * 4, stream);

    k_prep<<<PBLK, 256, 0, stream>>>(feat, dst, src, fcan, degp,
                                     esrc2, ovf, ovfc,
                                     W1, al1, ar1, res1, b1,
                                     g1g, g1b, g1m, g1v,
                                     b2v, g2g, g2b, g2m, g2v,
                                     bd1, gdg, gdb, gdm, gdv,
                                     flag, cst);

    k_layer1<<<L1BLK, 256, 0, stream>>>(fcan, W2, res2, al2, ar2, flag, cst,
                                        degp, esrc2, ovf, ovfc,
                                        F2, RS2, EL2, ER2);

    k_final<<<FBLK, 256, 0, stream>>>(Wd1, Wd2, bd2, flag, cst,
                                      degp, esrc2, ovf, ovfc,
                                      F2, RS2, EL2, ER2,
                                      (float*)d_out);

    k_pool2<<<NG, 256, 0, stream>>>(gid, RS2, (float*)d_out);
}

// Round 7
// 246.344 us; speedup vs baseline: 1.6895x; 1.6895x over previous
//
#include <hip/hip_runtime.h>
#include <hip/hip_bf16.h>
#include <hip/hip_fp16.h>

#define NN 50000
#define NE 800000
#define NG 64
#define C1 128    // H1*D1
#define D2 32
#define CAP 32    // capped slots per node; overflow handled exactly via ovf buffer
#define EPT 4     // edges per thread in k_prep (pipelined chains)
#define PBLK 782  // ceil(NE / (256*EPT))
#define L1BLK 1280 // k_layer1: 5 blocks/CU (27.1KB LDS cap) -> full residency + staging cut
#define BN_EPS 1e-5f

// ---- constant-block layout (float offsets inside cst) ----
#define CST_A   0
#define CST_B   2
#define CST_P   4
#define CST_Q   132
#define CST_R   260
#define CST_SC2 388
#define CST_RC2 420
#define CST_SD  452
#define CST_RD  580
#define CST_N   1024

// ---- workspace layout (4-byte-unit offsets inside d_ws), ~23 MiB ----
#define UO_DEGP  0                        // int[16*NN] padded: one counter per 64B line (zeroed)
#define UO_OVFC  800000                   // int[1]   (zeroed, padded)
#define ZERO_UNITS 800016
#define UO_FLAG  800016                   // int[1]
#define UO_CST   800032                   // float[CST_N]
#define UO_ESRC2 801056                   // ushort[CAP*NN] padded edge table (64B-aligned rows)
#define UO_OVF   1601056                  // int2[NE] overflow (dst,src)
#define UO_FCAN  3201056                  // float[NN]
#define UO_F2    3251056                  // ushort[D2*NN] bf16 (16B aligned)
#define UO_RS2   4051056                  // float[D2*NN]; overwritten with h2 by k_final
#define UO_EL2   5651056                  // float[NN]
#define UO_ER2   5701056                  // float[NN]

typedef _Float16 h2vec __attribute__((ext_vector_type(2)));

__device__ __forceinline__ float lrelu(float x) { return fmaxf(x, 0.2f * x); }
__device__ __forceinline__ float bu2f(unsigned int u) {
    union { unsigned int i; float f; } v; v.i = (u & 0xFFFFu) << 16; return v.f;
}
__device__ __forceinline__ unsigned short f2bu(float f) {
    union { float f; unsigned int i; } v; v.f = f;
    unsigned int r = v.i + 0x7FFFu + ((v.i >> 16) & 1u);
    return (unsigned short)(r >> 16);
}
__device__ __forceinline__ unsigned int packh2(float a, float b) {
    h2vec h; h.x = (_Float16)a; h.y = (_Float16)b;
    union { h2vec h; unsigned int u; } v; v.h = h; return v.u;
}
__device__ __forceinline__ h2vec as_h2(unsigned int u) {
    union { unsigned int u; h2vec h; } v; v.u = u; return v.h;
}
__device__ __forceinline__ float ldw(const void* p, int i, int bf) {
    return bf ? bu2f(((const unsigned short*)p)[i]) : ((const float*)p)[i];
}
__device__ __forceinline__ int sniff64(const unsigned int* fw, int l) {
    int cnt = 0;
    for (int j = l; j < 256; j += 64) {
        unsigned int b = (fw[j] >> 8) & 0x7Fu;
        cnt += (b >= 0x3Au && b <= 0x41u) ? 1 : 0;
    }
#pragma unroll
    for (int m = 32; m >= 1; m >>= 1) cnt += __shfl_xor(cnt, m);
    return (cnt > 128) ? 1 : 0;
}

// ---------------- edge-table build: single-pass, explicitly pipelined atomic chains ----------------
// (R5-verified: k_prep dropped out of top-5 with this structure; do not touch.)
__global__ __launch_bounds__(256) void k_prep(
                       const void* __restrict__ feat, const int* __restrict__ dst,
                       const int* __restrict__ src,
                       float* __restrict__ fcan, int* __restrict__ degp,
                       unsigned short* __restrict__ esrc2,
                       int2* __restrict__ ovf, int* __restrict__ ovfc,
                       const void* W1, const void* al1, const void* ar1,
                       const void* res1, const void* b1,
                       const void* g1g, const void* g1b, const void* g1m, const void* g1v,
                       const void* b2v, const void* g2g, const void* g2b,
                       const void* g2m, const void* g2v,
                       const void* bd1, const void* gdg, const void* gdb,
                       const void* gdm, const void* gdv,
                       int* __restrict__ flag, float* __restrict__ cst) {
    __shared__ int sBf;
    int t = threadIdx.x;
    if (t < 64) {
        int b = sniff64((const unsigned int*)feat, t);
        if (t == 0) sBf = b;
    }
    __syncthreads();
    int bf = sBf;

    if (blockIdx.x == 0) {     // fold tiny weights into fp32 constants (tree-parallel)
        if (t == 0) *flag = bf;
        if (t < 128) {
            float w1v = ldw(W1, t, bf);
            float pa = w1v * ldw(al1, t, bf);
            float pb = w1v * ldw(ar1, t, bf);
#pragma unroll
            for (int m = 32; m >= 1; m >>= 1) { pa += __shfl_xor(pa, m); pb += __shfl_xor(pb, m); }
            if ((t & 63) == 0) { cst[CST_A + (t >> 6)] = pa; cst[CST_B + (t >> 6)] = pb; }
            float sc = rsqrtf(ldw(g1v, t, bf) + BN_EPS) * ldw(g1g, t, bf);
            cst[CST_P + t] = w1v * sc;
            cst[CST_Q + t] = ldw(res1, t, bf) * sc;
            cst[CST_R + t] = (ldw(b1, t, bf) - ldw(g1m, t, bf)) * sc + ldw(g1b, t, bf);
            if (t < D2) {
                float s2 = rsqrtf(ldw(g2v, t, bf) + BN_EPS) * ldw(g2g, t, bf);
                cst[CST_SC2 + t] = s2;
                cst[CST_RC2 + t] = (ldw(b2v, t, bf) - ldw(g2m, t, bf)) * s2 + ldw(g2b, t, bf);
            }
            float sd = rsqrtf(ldw(gdv, t, bf) + BN_EPS) * ldw(gdg, t, bf);
            cst[CST_SD + t] = sd;
            cst[CST_RD + t] = (ldw(bd1, t, bf) - ldw(gdm, t, bf)) * sd + ldw(gdb, t, bf);
        }
    }

    // fcan conversion, grid-stride (<=1 iter/thread at this grid)
    for (int k = blockIdx.x * 256 + t; k < NN; k += PBLK * 256)
        fcan[k] = ldw(feat, k, bf);

    // phase a: load EPT edges (independent coalesced loads)
    int base = blockIdx.x * (256 * EPT) + t;
    int dv[EPT], sv[EPT];
    bool vv[EPT];
#pragma unroll
    for (int j = 0; j < EPT; ++j) {
        int k = base + j * 256;
        vv[j] = (k < NE);
        dv[j] = vv[j] ? dst[k] : 0;
        sv[j] = vv[j] ? src[k] : 0;
    }
    // phase b: issue all slot atomics back-to-back (independent round trips)
    int slot[EPT];
#pragma unroll
    for (int j = 0; j < EPT; ++j)
        if (vv[j]) slot[j] = atomicAdd(&degp[dv[j] << 4], 1);
    __builtin_amdgcn_sched_barrier(0);   // keep stores from sinking between atomic issues
    // phase c: consume slots
#pragma unroll
    for (int j = 0; j < EPT; ++j) {
        if (vv[j]) {
            if (slot[j] < CAP) {
                esrc2[dv[j] * CAP + slot[j]] = (unsigned short)sv[j];
            } else {
                int p = atomicAdd(ovfc, 1);    // rare
                ovf[p] = make_int2(dv[j], sv[j]);
            }
        }
    }
}

// ---------------- layer-1: 1280 blocks = 5/CU (LDS-cap residency) + staging amortized ----------
__global__ __launch_bounds__(256) void k_layer1(
        const float* __restrict__ fcan, const void* W2, const void* res2,
        const void* al2, const void* ar2,
        const int* __restrict__ flag, const float* __restrict__ cst,
        const int* __restrict__ degp, const unsigned short* __restrict__ esrc2,
        const int2* __restrict__ ovf, const int* __restrict__ ovfc,
        unsigned short* __restrict__ F2, float* __restrict__ RS2,
        float* __restrict__ EL2, float* __restrict__ ER2) {
    __shared__ unsigned int sW2pk[32 * 66];  // [l][cw], (c,c+64) f16 pairs
    __shared__ unsigned int sR2pk[32 * 66];
    __shared__ unsigned int sH1pk[32 * 66];
    __shared__ float sP[C1], sQ[C1], sR[C1];
    __shared__ float sAl[D2], sAr[D2];
    int t = threadIdx.x;
    int bf = *flag;
    for (int u = t; u < 2048; u += 256) {
        int cw = u >> 5, l2 = u & 31;
        sW2pk[l2 * 66 + cw] = packh2(ldw(W2, cw * D2 + l2, bf),
                                     ldw(W2, (cw + 64) * D2 + l2, bf));
        sR2pk[l2 * 66 + cw] = packh2(ldw(res2, cw * D2 + l2, bf),
                                     ldw(res2, (cw + 64) * D2 + l2, bf));
    }
    if (t < C1) { sP[t] = cst[CST_P + t]; sQ[t] = cst[CST_Q + t]; sR[t] = cst[CST_R + t]; }
    if (t < D2) { sAl[t] = ldw(al2, t, bf); sAr[t] = ldw(ar2, t, bf); }
    float A0 = cst[CST_A + 0], A1 = cst[CST_A + 1];
    float B0 = cst[CST_B + 0], B1 = cst[CST_B + 1];
    __syncthreads();

    int l = t & 31;
    int g = t >> 5;
    int w = t >> 6, half = (t >> 5) & 1, nb0 = w * 8 + half * 4;

    for (int base = blockIdx.x * 32; base < NN; base += L1BLK * 32) {
        int dcap[4], draw[4];
        float fiK[4];
#pragma unroll
        for (int k = 0; k < 4; ++k) {
            int i = base + g * 4 + k;
            if (i < NN) {
                draw[k] = degp[i << 4];
                dcap[k] = draw[k] < CAP ? draw[k] : CAP;
                fiK[k] = fcan[i];
            } else { draw[k] = 0; dcap[k] = 0; fiK[k] = 0.0f; }
        }
        float S0[4], S1[4], N0[4], N1[4];
#pragma unroll
        for (int k = 0; k < 4; ++k) { S0[k] = S1[k] = N0[k] = N1[k] = 0.0f; }
        int sA[4];
#pragma unroll
        for (int k = 0; k < 4; ++k)
            sA[k] = (l < dcap[k]) ? (int)esrc2[(base + g * 4 + k) * CAP + l] : 0;
        float fA[4];
#pragma unroll
        for (int k = 0; k < 4; ++k) fA[k] = fcan[sA[k]];
#pragma unroll
        for (int k = 0; k < 4; ++k) {
            if (l < dcap[k]) {
                float w0 = __expf(lrelu(A0 * fA[k] + B0 * fiK[k]));
                float w1 = __expf(lrelu(A1 * fA[k] + B1 * fiK[k]));
                S0[k] += w0; N0[k] += w0 * fA[k];
                S1[k] += w1; N1[k] += w1 * fA[k];
            }
        }
        // rare overflow edges (deg > CAP)
#pragma unroll
        for (int k = 0; k < 4; ++k) {
            if (draw[k] > CAP) {
                int i = base + g * 4 + k;
                int novf = *ovfc;
                for (int p = l; p < novf; p += 32) {
                    int2 o = ovf[p];
                    if (o.x == i) {
                        float fs = fcan[o.y];
                        float w0 = __expf(lrelu(A0 * fs + B0 * fiK[k]));
                        float w1 = __expf(lrelu(A1 * fs + B1 * fiK[k]));
                        S0[k] += w0; N0[k] += w0 * fs;
                        S1[k] += w1; N1[k] += w1 * fs;
                    }
                }
            }
        }
#pragma unroll
        for (int m = 16; m >= 1; m >>= 1) {
#pragma unroll
            for (int k = 0; k < 4; ++k) {
                S0[k] += __shfl_xor(S0[k], m); N0[k] += __shfl_xor(N0[k], m);
                S1[k] += __shfl_xor(S1[k], m); N1[k] += __shfl_xor(N1[k], m);
            }
        }
#pragma unroll
        for (int k = 0; k < 4; ++k) {
            int slot = g * 4 + k;
            float T0 = S0[k] > 0.0f ? N0[k] / S0[k] : 0.0f;
            float T1 = S1[k] > 0.0f ? N1[k] / S1[k] : 0.0f;
            float h0  = fmaxf(sP[l]      * T0 + sQ[l]      * fiK[k] + sR[l],      0.0f);
            float h1v = fmaxf(sP[l + 32] * T0 + sQ[l + 32] * fiK[k] + sR[l + 32], 0.0f);
            float h2v = fmaxf(sP[l + 64] * T1 + sQ[l + 64] * fiK[k] + sR[l + 64], 0.0f);
            float h3v = fmaxf(sP[l + 96] * T1 + sQ[l + 96] * fiK[k] + sR[l + 96], 0.0f);
            sH1pk[slot * 66 + l]      = packh2(h0,  h2v);   // (c, c+64) f16 pair
            sH1pk[slot * 66 + l + 32] = packh2(h1v, h3v);
        }
        __syncthreads();

        // --- phase 2: v_dot2_f32_f16 — one inst per (c,c+64) pair, fp32 accumulate
        float aF[4] = {0.f, 0.f, 0.f, 0.f}, aR[4] = {0.f, 0.f, 0.f, 0.f};
        for (int cw = 0; cw < 64; cw += 2) {
            uint2 wq = *(const uint2*)&sW2pk[l * 66 + cw];
            uint2 rq = *(const uint2*)&sR2pk[l * 66 + cw];
#pragma unroll
            for (int n = 0; n < 4; ++n) {
                uint2 hq = *(const uint2*)&sH1pk[(nb0 + n) * 66 + cw];   // broadcast
                aF[n] = __builtin_amdgcn_fdot2(as_h2(hq.x), as_h2(wq.x),
                        __builtin_amdgcn_fdot2(as_h2(hq.y), as_h2(wq.y), aF[n], false), false);
                aR[n] = __builtin_amdgcn_fdot2(as_h2(hq.x), as_h2(rq.x),
                        __builtin_amdgcn_fdot2(as_h2(hq.y), as_h2(rq.y), aR[n], false), false);
            }
        }
#pragma unroll
        for (int n = 0; n < 4; ++n) {
            int i = base + nb0 + n;
            if (i < NN) {
                float elp = aF[n] * sAl[l], erp = aF[n] * sAr[l];
#pragma unroll
                for (int m = 16; m >= 1; m >>= 1) {
                    elp += __shfl_xor(elp, m);
                    erp += __shfl_xor(erp, m);
                }
                if (l == 0) { EL2[i] = elp; ER2[i] = erp; }
                F2[(size_t)i * D2 + l]  = f2bu(aF[n]);
                RS2[(size_t)i * D2 + l] = aR[n];
            }
        }
        __syncthreads();   // H1pk reused next tile
    }
}

// ---------------- layer-2 gather + decoder: EXACT R5 body (straight-line, verified 49.4us) ----
// R6's grid-stride wrap of this body caused a 410MB scratch-traffic anomaly (rule #20) — keep
// this straight-line; do NOT loop it.
__global__ __launch_bounds__(256, 8) void k_final(
        const void* Wd1, const void* Wd2, const void* bd2,
        const int* __restrict__ flag, const float* __restrict__ cst,
        const int* __restrict__ degp, const unsigned short* __restrict__ esrc2,
        const int2* __restrict__ ovf, const int* __restrict__ ovfc,
        const unsigned short* __restrict__ F2, float* __restrict__ RS2,
        const float* __restrict__ EL2, const float* __restrict__ ER2,
        float* __restrict__ out) {
    __shared__ float sWd1x[4096];        // [d][lane][4] = {W[d][l], W[d][l+32], W[d][l+64], W[d][l+96]}
    __shared__ unsigned int sWS[8 * 64]; // per-group (w,s) pairs
    int t = threadIdx.x;
    int bf = *flag;
    for (int u = t; u < 4096; u += 256) {
        int d = u >> 7, lq = (u >> 2) & 31, j = u & 3;
        sWd1x[u] = ldw(Wd1, d * C1 + j * 32 + lq, bf);
    }

    int i = (blockIdx.x * 256 + t) >> 5;
    int l = t & 31;
    int nb = t >> 5;

    // per-lane epilogue constants (registers, not LDS)
    float sc2 = cst[CST_SC2 + l], rc2 = cst[CST_RC2 + l];
    float sd0 = cst[CST_SD + l],      rd0 = cst[CST_RD + l];
    float sd1 = cst[CST_SD + l + 32], rd1 = cst[CST_RD + l + 32];
    float sd2 = cst[CST_SD + l + 64], rd2 = cst[CST_RD + l + 64];
    float sd3 = cst[CST_SD + l + 96], rd3 = cst[CST_RD + l + 96];
    float wd2_0 = ldw(Wd2, l, bf),      wd2_1 = ldw(Wd2, l + 32, bf);
    float wd2_2 = ldw(Wd2, l + 64, bf), wd2_3 = ldw(Wd2, l + 96, bf);
    __syncthreads();

    float eri = ER2[i];
    int dr = degp[i << 4];
    int dcap = dr < CAP ? dr : CAP;
    const unsigned short* row = &esrc2[i * CAP];

    // --- per-lane w: lane l owns edge l (exp computed ONCE per edge)
    int sMy = 0; float wMy = 0.0f;
    if (l < dcap) {
        sMy = (int)row[l];
        wMy = __expf(lrelu(EL2[sMy] + eri));
    }
    float S = wMy;
#pragma unroll
    for (int m = 16; m >= 1; m >>= 1) S += __shfl_xor(S, m);
    sWS[nb * 64 + 2 * l]     = __float_as_uint(wMy);
    sWS[nb * 64 + 2 * l + 1] = (unsigned int)sMy;

    float aF0 = 0.f, aF1 = 0.f, aF2 = 0.f, aF3 = 0.f;
    int e = 0;
    for (; e + 3 < dcap; e += 4) {
        uint2 p0 = *(const uint2*)&sWS[nb * 64 + 2 * e];
        uint2 p1 = *(const uint2*)&sWS[nb * 64 + 2 * (e + 1)];
        uint2 p2 = *(const uint2*)&sWS[nb * 64 + 2 * (e + 2)];
        uint2 p3 = *(const uint2*)&sWS[nb * 64 + 2 * (e + 3)];
        float v0 = bu2f(F2[(size_t)p0.y * D2 + l]);
        float v1 = bu2f(F2[(size_t)p1.y * D2 + l]);
        float v2 = bu2f(F2[(size_t)p2.y * D2 + l]);
        float v3 = bu2f(F2[(size_t)p3.y * D2 + l]);
        aF0 = fmaf(__uint_as_float(p0.x), v0, aF0);
        aF1 = fmaf(__uint_as_float(p1.x), v1, aF1);
        aF2 = fmaf(__uint_as_float(p2.x), v2, aF2);
        aF3 = fmaf(__uint_as_float(p3.x), v3, aF3);
    }
    for (; e < dcap; ++e) {
        uint2 p = *(const uint2*)&sWS[nb * 64 + 2 * e];
        aF0 = fmaf(__uint_as_float(p.x), bu2f(F2[(size_t)p.y * D2 + l]), aF0);
    }
    if (dr > CAP) {
        int novf = *ovfc;
        for (int p = 0; p < novf; ++p) {
            int2 o = ovf[p];
            if (o.x == i) {
                float wA = __expf(lrelu(EL2[o.y] + eri));
                S += wA;
                aF0 = fmaf(wA, bu2f(F2[(size_t)o.y * D2 + l]), aF0);
            }
        }
    }
    float aF = (aF0 + aF1) + (aF2 + aF3);
    float inv = S > 0.0f ? 1.0f / S : 0.0f;

    float h2 = fmaxf((aF * inv + RS2[(size_t)i * D2 + l]) * sc2 + rc2, 0.0f);
    RS2[(size_t)i * D2 + l] = h2;

    const float4* Wx = (const float4*)sWd1x;
    float ac0 = 0.0f, ac1 = 0.0f, ac2 = 0.0f, ac3 = 0.0f;
#pragma unroll
    for (int d = 0; d < D2; ++d) {
        float h = __shfl(h2, d, 32);          // broadcast lane d's h2 within the 32-lane group
        float4 wv = Wx[d * 32 + l];           // one ds_read_b128, conflict-free
        ac0 = fmaf(h, wv.x, ac0);
        ac1 = fmaf(h, wv.y, ac1);
        ac2 = fmaf(h, wv.z, ac2);
        ac3 = fmaf(h, wv.w, ac3);
    }
    float rec = fmaxf(ac0 * sd0 + rd0, 0.0f) * wd2_0
              + fmaxf(ac1 * sd1 + rd1, 0.0f) * wd2_1
              + fmaxf(ac2 * sd2 + rd2, 0.0f) * wd2_2
              + fmaxf(ac3 * sd3 + rd3, 0.0f) * wd2_3;
#pragma unroll
    for (int m = 16; m >= 1; m >>= 1) rec += __shfl_xor(rec, m);
    if (l == 0) out[NG * D2 + i] = rec + ldw(bd2, 0, bf);
}

// ---------------- graph mean pool: one block per graph, direct write ----------
__global__ __launch_bounds__(256) void k_pool2(const int* __restrict__ gid,
                                               const float* __restrict__ H2,
                                               float* __restrict__ out) {
    __shared__ int sLo, sHi;
    __shared__ float sAcc[32 * 32];
    int g = blockIdx.x;
    int t = threadIdx.x;
    if (t == 0) {
        int lo = 0, hi = NN;
        while (lo < hi) { int m = (lo + hi) >> 1; if (gid[m] < g) lo = m + 1; else hi = m; }
        sLo = lo;
        lo = 0; hi = NN;
        while (lo < hi) { int m = (lo + hi) >> 1; if (gid[m] < g + 1) lo = m + 1; else hi = m; }
        sHi = lo;
    }
    __syncthreads();
    int lo = sLo, hi = sHi;
    int q = t & 7;
    int row = t >> 3;
    float4 acc = make_float4(0.f, 0.f, 0.f, 0.f);
    for (int i = lo + row; i < hi; i += 32) {
        float4 v = ((const float4*)&H2[(size_t)i * D2])[q];
        acc.x += v.x; acc.y += v.y; acc.z += v.z; acc.w += v.w;
    }
    *(float4*)&sAcc[row * 32 + 4 * q] = acc;
    __syncthreads();
    if (t < 32) {
        float a = 0.0f;
        for (int r = 0; r < 32; ++r) a += sAcc[r * 32 + t];
        float c = (float)(hi - lo);
        out[g * D2 + t] = a / fmaxf(c, 1.0f);
    }
}

extern "C" void kernel_launch(void* const* d_in, const int* in_sizes, int n_in,
                              void* d_out, int out_size, void* d_ws, size_t ws_size,
                              hipStream_t stream) {
    const void* feat = d_in[0];
    const void* W1 = d_in[1];  const void* al1 = d_in[2];  const void* ar1 = d_in[3];
    const void* res1 = d_in[4]; const void* b1 = d_in[5];
    const void* g1g = d_in[6]; const void* g1b = d_in[7];
    const void* g1m = d_in[8]; const void* g1v = d_in[9];
    const void* W2 = d_in[10]; const void* al2 = d_in[11]; const void* ar2 = d_in[12];
    const void* res2 = d_in[13]; const void* b2v = d_in[14];
    const void* g2g = d_in[15]; const void* g2b = d_in[16];
    const void* g2m = d_in[17]; const void* g2v = d_in[18];
    const void* Wd1 = d_in[19]; const void* bd1 = d_in[20];
    const void* gdg = d_in[21]; const void* gdb = d_in[22];
    const void* gdm = d_in[23]; const void* gdv = d_in[24];
    const void* Wd2 = d_in[25]; const void* bd2 = d_in[26];
    const int* src = (const int*)d_in[27];
    const int* dst = (const int*)d_in[28];
    const int* gid = (const int*)d_in[29];

    unsigned int* wsu = (unsigned int*)d_ws;
    int* degp   = (int*)(wsu + UO_DEGP);
    int* ovfc   = (int*)(wsu + UO_OVFC);
    int* flag   = (int*)(wsu + UO_FLAG);
    float* cst  = (float*)(wsu + UO_CST);
    unsigned short* esrc2 = (unsigned short*)(wsu + UO_ESRC2);
    int2* ovf   = (int2*)(wsu + UO_OVF);
    float* fcan = (float*)(wsu + UO_FCAN);
    unsigned short* F2 = (unsigned short*)(wsu + UO_F2);
    float* RS2  = (float*)(wsu + UO_RS2);
    float* EL2  = (float*)(wsu + UO_EL2);
    float* ER2  = (float*)(wsu + UO_ER2);

    hipMemsetAsync(d_ws, 0, (size_t)ZERO_UNITS * 4, stream);

    k_prep<<<PBLK, 256, 0, stream>>>(feat, dst, src, fcan, degp,
                                     esrc2, ovf, ovfc,
                                     W1, al1, ar1, res1, b1,
                                     g1g, g1b, g1m, g1v,
                                     b2v, g2g, g2b, g2m, g2v,
                                     bd1, gdg, gdb, gdm, gdv,
                                     flag, cst);

    k_layer1<<<L1BLK, 256, 0, stream>>>(fcan, W2, res2, al2, ar2, flag, cst,
                                        degp, esrc2, ovf, ovfc,
                                        F2, RS2, EL2, ER2);

    k_final<<<(NN * 32) / 256, 256, 0, stream>>>(Wd1, Wd2, bd2, flag, cst,
                                                 degp, esrc2, ovf, ovfc,
                                                 F2, RS2, EL2, ER2,
                                                 (float*)d_out);

    k_pool2<<<NG, 256, 0, stream>>>(gid, RS2, (float*)d_out);
}